// Round 1
// baseline (1409.194 us; speedup 1.0000x reference)
//
#include <hip/hip_runtime.h>
#include <hip/hip_bf16.h>

#define NALGOS 64
#define NTASKS 256
#define TSTEPS 4096
#define CHUNK  256   // steps per expand block
#define NCHUNK (TSTEPS / CHUNK)   // 16
#define SUB    32    // steps per LDS sub-tile flush
#define TPAD   33    // LDS row pitch (bank-conflict pad)

// -------- Phase 1: driver. One wave per algorithm. Computes g[a,t] and
// res-state checkpoints every CHUNK steps. No barriers: intra-wave readlane.
__global__ __launch_bounds__(64) void driver_kernel(
    const int* __restrict__ lx, const float* __restrict__ tmat,
    const float* __restrict__ diff, const float* __restrict__ eff_v,
    const float* __restrict__ mem_v, const float* __restrict__ boost_v,
    float* __restrict__ g_arr, float* __restrict__ ckpt) {
  const int a = blockIdx.x;
  const int l = threadIdx.x;          // 0..63, owns columns 4l..4l+3
  const float eff = eff_v[a];
  const float mem = mem_v[a];
  const float boost = boost_v[a];

  const float4 d4 = ((const float4*)diff)[l];
  const float k0 = 1.0f / d4.x, k1 = 1.0f / d4.y, k2 = 1.0f / d4.z, k3 = 1.0f / d4.w;

  float r0 = 0.f, r1 = 0.f, r2 = 0.f, r3 = 0.f;
  const float4* rows = (const float4*)tmat;   // row r: rows[r*64 + l]
  float* gout = g_arr + (size_t)a * TSTEPS;
  float* ck   = ckpt  + (size_t)a * NCHUNK * NTASKS;

  float d = 0.f;                       // d_0 = sig_{-1} = 0
  int task_c = lx[0];                  // task for step t
  int task_n = lx[1];                  // task for step t+1 (prefetched)
  float4 tm_c = rows[task_c * 64 + l];

  for (int t = 0; t < TSTEPS; ++t) {
    // prefetch two steps of lx, one step of row data
    int task_nn = (t + 2 < TSTEPS) ? lx[t + 2] : 0;
    float4 tm_n = rows[task_n * 64 + l];

    float g = fmaf(boost, d, eff);
    if (l == 0) gout[t] = g;

    r0 = fmaf(r0, mem, tm_c.x * g);
    r1 = fmaf(r1, mem, tm_c.y * g);
    r2 = fmaf(r2, mem, tm_c.z * g);
    r3 = fmaf(r3, mem, tm_c.w * g);

    if (((t + 1) & (CHUNK - 1)) == 0 && (t + 1) < TSTEPS) {
      float4 s; s.x = r0; s.y = r1; s.z = r2; s.w = r3;
      ((float4*)(ck + ((t + 1) >> 8) * NTASKS))[l] = s;
    }

    // d_{t+1} = sigmoid-transform of res_t at column task_{t+1}
    int j = task_n & 3;
    float r = (j < 2) ? ((j == 0) ? r0 : r1) : ((j == 2) ? r2 : r3);
    float k = (j < 2) ? ((j == 0) ? k0 : k1) : ((j == 2) ? k2 : k3);
    float sig = 2.0f / (1.0f + __expf(-r * k)) - 1.0f;
    int ol = __builtin_amdgcn_readfirstlane(task_n >> 2);
    d = __uint_as_float(__builtin_amdgcn_readlane(__float_as_uint(sig), ol));

    task_c = task_n; tm_c = tm_n; task_n = task_nn;
  }
}

// -------- Phase 2: expand. block = (chunk, algorithm); thread = column n.
// Replays the linear recurrence from the exact checkpoint, computes sigmoids,
// stages in LDS, flushes with t-contiguous coalesced stores.
__global__ __launch_bounds__(256) void expand_kernel(
    const int* __restrict__ lx, const float* __restrict__ tmat,
    const float* __restrict__ diff, const float* __restrict__ mem_v,
    const float* __restrict__ g_arr, const float* __restrict__ ckpt,
    float* __restrict__ out) {
  const int c = blockIdx.x;   // chunk 0..15
  const int a = blockIdx.y;   // algorithm 0..63
  const int n = threadIdx.x;  // column 0..255

  const float mem = mem_v[a];
  const float kk = 1.0f / diff[n];
  float res = (c == 0) ? 0.f
                       : ckpt[((size_t)a * NCHUNK + c) * NTASKS + n];
  const float* g_base = g_arr + (size_t)a * TSTEPS;

  __shared__ float tile[NTASKS * TPAD];

  const size_t obase = ((size_t)a * NTASKS + n) * (TSTEPS + 1);
  if (c == 0) out[obase] = 0.f;   // t=0 plane of zeros

  const int t0 = c * CHUNK;
  for (int tb = 0; tb < CHUNK / SUB; ++tb) {
    const int tbase = t0 + tb * SUB;
#pragma unroll 8
    for (int ts = 0; ts < SUB; ++ts) {
      const int t = tbase + ts;
      float g = g_base[t];                       // uniform
      int task = lx[t];                          // uniform
      float tm = tmat[task * NTASKS + n];        // coalesced
      res = fmaf(res, mem, tm * g);
      float sig = 2.0f / (1.0f + __expf(-res * kk)) - 1.0f;
      tile[n * TPAD + ts] = sig;
    }
    __syncthreads();
    // flush 256 rows x 32 cols, t-contiguous per row
    const int row0 = threadIdx.x >> 5;  // 0..7
    const int col  = threadIdx.x & 31;
    for (int rr = 0; rr < NTASKS; rr += 8) {
      const int row = row0 + rr;
      out[((size_t)a * NTASKS + row) * (TSTEPS + 1) + tbase + col + 1] =
          tile[row * TPAD + col];
    }
    __syncthreads();
  }
}

extern "C" void kernel_launch(void* const* d_in, const int* in_sizes, int n_in,
                              void* d_out, int out_size, void* d_ws, size_t ws_size,
                              hipStream_t stream) {
  const int*   lx    = (const int*)d_in[0];
  const float* tmat  = (const float*)d_in[1];
  const float* diff  = (const float*)d_in[2];
  const float* eff   = (const float*)d_in[3];
  const float* mem   = (const float*)d_in[4];
  const float* boost = (const float*)d_in[5];
  float* out = (float*)d_out;

  float* g_arr = (float*)d_ws;                         // 64*4096 f32 = 1 MB
  float* ckpt  = g_arr + (size_t)NALGOS * TSTEPS;      // 64*16*256 f32 = 1 MB

  driver_kernel<<<NALGOS, 64, 0, stream>>>(lx, tmat, diff, eff, mem, boost,
                                           g_arr, ckpt);
  expand_kernel<<<dim3(NCHUNK, NALGOS), 256, 0, stream>>>(
      lx, tmat, diff, mem, g_arr, ckpt, out);
}

// Round 2
// 729.365 us; speedup vs baseline: 1.9321x; 1.9321x over previous
//
#include <hip/hip_runtime.h>
#include <hip/hip_bf16.h>

#define NALGOS 64
#define NTASKS 256
#define TSTEPS 4096
#define CHUNK  256                 // steps per expand block
#define NCHUNK (TSTEPS / CHUNK)    // 16
#define SUB    64                  // steps per expand LDS sub-tile
#define TP     257                 // expand tile pitch (t-major), odd -> conflict-free
#define LOG2E  1.44269504f

// ---------------- Phase 1: driver --------------------------------------------
// One wave per algorithm. Serial chain per step: rcp -> fma -> exp2 -> add.
// All lx-dependent constants precomputed into LDS tables; tm rows in a 4-deep
// register pipeline; g captured in a rotating register, flushed every 64 steps.
__global__ __launch_bounds__(64) void driver_kernel(
    const int* __restrict__ lx, const float* __restrict__ tmat,
    const float* __restrict__ diff, const float* __restrict__ eff_v,
    const float* __restrict__ mem_v, const float* __restrict__ boost_v,
    float* __restrict__ g_arr, float* __restrict__ ckpt) {
  __shared__ int    lx_s[TSTEPS + 8];
  __shared__ float  c_s[NTASKS];
  __shared__ float4 ctab[TSTEPS + 8];   // {c'_t, B_t, A0_t, lx[t] | lx[t+2]<<16}

  const int a = blockIdx.x;
  const int l = threadIdx.x;
  const float eff   = eff_v[a];
  const float mem   = mem_v[a];
  const float boost = boost_v[a];
  const float e0 = eff - boost;
  const float b2 = 2.0f * boost;

  // stage lx into LDS (coalesced)
#pragma unroll 8
  for (int k = 0; k < TSTEPS / 64; ++k) lx_s[k * 64 + l] = lx[k * 64 + l];
  if (l < 8) lx_s[TSTEPS + l] = 0;
  // c_s[n] = -log2e / diff[n]
#pragma unroll
  for (int k = 0; k < NTASKS / 64; ++k) {
    float dk = diff[k * 64 + l];
    c_s[k * 64 + l] = -LOG2E / dk;
  }
  __syncthreads();

  // build ctab
#pragma unroll 4
  for (int k = 0; k < TSTEPS / 64; ++k) {
    int i  = k * 64 + l;
    int t0 = lx_s[i];
    int t1 = (i + 1 < TSTEPS) ? lx_s[i + 1] : 0;
    int t2 = (i + 2 < TSTEPS) ? lx_s[i + 2] : 0;
    float q  = tmat[t0 * NTASKS + t1];
    float cp = c_s[t1];
    float4 e;
    e.x = cp;
    e.y = b2 * cp * q;
    e.z = e0 * cp * q;
    e.w = __int_as_float(t0 | (t2 << 16));
    ctab[i] = e;
  }
  if (l < 8) ctab[TSTEPS + l] = make_float4(0.f, 0.f, 0.f, __int_as_float(0));
  __syncthreads();

  const float4* rows = (const float4*)tmat;  // row r: rows[r*64 + l] (4 cols/lane)
  float* gout = g_arr + (size_t)a * TSTEPS;
  float* ck   = ckpt  + (size_t)a * NCHUNK * NTASKS;

  float r0 = 0.f, r1 = 0.f, r2 = 0.f, r3 = 0.f;
  float u = 2.0f;                 // 1 + exp2(0): w_{-1} = 0.5 -> g_0 = eff
  float keep_g = 0.f;

  float4 ct_cur = ctab[0];
  float4 ct_n1  = ctab[1];
  float4 ct_n2  = ctab[2];
  float  A = ct_cur.z;            // A_0 = A0_0 (p_0 = 0)

  float4 tm0 = rows[lx_s[0] * 64 + l];
  float4 tm1 = rows[lx_s[1] * 64 + l];
  float4 tm2 = rows[lx_s[2] * 64 + l];
  float4 tm3 = rows[lx_s[3] * 64 + l];

#pragma unroll 4
  for (int t = 0; t < TSTEPS; ++t) {
    // ---- main serial chain ----
    float w   = __builtin_amdgcn_rcpf(u);        // w_{t-1} = sigma(x_{t-1})
    float g   = fmaf(b2, w, e0);                 // g_t
    float arg = fmaf(ct_cur.y, w, A);            // c'_t * res_t[lx[t+1]]
    float ev  = __builtin_amdgcn_exp2f(arg);
    u = 1.0f + ev;                               // u_t

    // ---- off-chain ----
    keep_g = ((t & 63) == l) ? g : keep_g;

    r0 = fmaf(r0, mem, tm0.x * g);
    r1 = fmaf(r1, mem, tm0.y * g);
    r2 = fmaf(r2, mem, tm0.z * g);
    r3 = fmaf(r3, mem, tm0.w * g);

    // select res_t[lx[t+2]] and broadcast from owner lane
    int sb   = __float_as_int(ct_cur.w);
    int j2   = (sb >> 16) & 0xffff;              // lx[t+2]
    int lane = j2 >> 2;
    float h01  = (j2 & 1) ? r1 : r0;
    float h23  = (j2 & 1) ? r3 : r2;
    float hsel = (j2 & 2) ? h23 : h01;
    float bro = __uint_as_float(
        __builtin_amdgcn_readlane(__float_as_uint(hsel), lane));
    float p = mem * bro;                         // p_{t+1}
    A = fmaf(ct_n1.x, p, ct_n1.z);               // A_{t+1}

    // rotate pipelines, prefetch
    ct_cur = ct_n1; ct_n1 = ct_n2; ct_n2 = ctab[t + 3];
    int nrow = lx_s[t + 4];
    tm0 = tm1; tm1 = tm2; tm2 = tm3;
    tm3 = rows[nrow * 64 + l];

    if ((t & 63) == 63) gout[t - 63 + l] = keep_g;
    if ((t & 255) == 255 && t < TSTEPS - 1) {
      float4 s; s.x = r0; s.y = r1; s.z = r2; s.w = r3;
      ((float4*)(ck + ((t + 1) >> 8) * NTASKS))[l] = s;
    }
  }
}

// ---------------- Phase 2: expand --------------------------------------------
// block = (chunk, algorithm); thread = column n. t-major LDS tile, float4
// stores along t (256-B contiguous runs; same-block runs merge in L2).
__global__ __launch_bounds__(256) void expand_kernel(
    const int* __restrict__ lx, const float* __restrict__ tmat,
    const float* __restrict__ diff, const float* __restrict__ mem_v,
    const float* __restrict__ g_arr, const float* __restrict__ ckpt,
    float* __restrict__ out) {
  __shared__ float tile[SUB * TP];    // t-major: tile[ts*TP + n]
  __shared__ int   lx_c[CHUNK];
  __shared__ float g_c[CHUNK];

  const int c = blockIdx.x;   // chunk 0..15
  const int a = blockIdx.y;   // algorithm 0..63
  const int n = threadIdx.x;  // column 0..255

  const float mem = mem_v[a];
  const float cn  = -LOG2E / diff[n];
  float res = (c == 0) ? 0.f : ckpt[((size_t)a * NCHUNK + c) * NTASKS + n];

  const int t0 = c * CHUNK;
  lx_c[n] = lx[t0 + n];
  g_c[n]  = g_arr[(size_t)a * TSTEPS + t0 + n];
  __syncthreads();

  if (c == 0) out[((size_t)a * NTASKS + n) * (TSTEPS + 1)] = 0.f;

  const int tq   = threadIdx.x & 15;   // t-quad within run
  const int rloc = threadIdx.x >> 4;   // 0..15

  for (int tb = 0; tb < CHUNK; tb += SUB) {
    // compute 64 steps for own column
#pragma unroll 8
    for (int ts = 0; ts < SUB; ++ts) {
      int   task = lx_c[tb + ts];
      float g    = g_c[tb + ts];
      float tm   = tmat[task * NTASKS + n];
      res = fmaf(res, mem, tm * g);
      float w = __builtin_amdgcn_rcpf(
          1.0f + __builtin_amdgcn_exp2f(cn * res));
      tile[ts * TP + n] = fmaf(2.0f, w, -1.0f);   // sig
    }
    __syncthreads();
    // flush: 16 rows per iteration, float4 along t
    for (int rr = 0; rr < NTASKS; rr += 16) {
      const int row = rr + rloc;
      float v0 = tile[(4 * tq + 0) * TP + row];
      float v1 = tile[(4 * tq + 1) * TP + row];
      float v2 = tile[(4 * tq + 2) * TP + row];
      float v3 = tile[(4 * tq + 3) * TP + row];
      float4 v = make_float4(v0, v1, v2, v3);
      float* dst = &out[((size_t)a * NTASKS + row) * (TSTEPS + 1) +
                        t0 + tb + 4 * tq + 1];
      __builtin_memcpy(dst, &v, 16);   // dword-aligned wide store
    }
    __syncthreads();
  }
}

extern "C" void kernel_launch(void* const* d_in, const int* in_sizes, int n_in,
                              void* d_out, int out_size, void* d_ws, size_t ws_size,
                              hipStream_t stream) {
  const int*   lx    = (const int*)d_in[0];
  const float* tmat  = (const float*)d_in[1];
  const float* diff  = (const float*)d_in[2];
  const float* eff   = (const float*)d_in[3];
  const float* mem   = (const float*)d_in[4];
  const float* boost = (const float*)d_in[5];
  float* out = (float*)d_out;

  float* g_arr = (float*)d_ws;                      // 64*4096 f32 = 1 MB
  float* ckpt  = g_arr + (size_t)NALGOS * TSTEPS;   // 64*16*256 f32 = 1 MB

  driver_kernel<<<NALGOS, 64, 0, stream>>>(lx, tmat, diff, eff, mem, boost,
                                           g_arr, ckpt);
  expand_kernel<<<dim3(NCHUNK, NALGOS), 256, 0, stream>>>(
      lx, tmat, diff, mem, g_arr, ckpt, out);
}